// Round 13
// baseline (134.222 us; speedup 1.0000x reference)
//
#include <hip/hip_runtime.h>

#define E_N 30000
#define KDIM 1024
#define E_DIRN 65536
#define E_UNDN 65536
#define E_EKN 120000
#define NB (1024 + 1024 + E_N)            // 32048 bins
#define TOT_E (E_DIRN + E_UNDN + E_EKN)   // 251072
#define ZERON (3 * KDIM + NB)             // zdot + counts words to zero
#define CAPK 192                          // per-bin capacity, dir/und (mean 64, max~104)
#define CAPE 32                           // per-bin capacity, ek (mean 4, P(>=32)~1e-18)
#define EKBASE (2048 * CAPK)              // 393216
#define NEDGE_SLOTS (EKBASE + E_N * CAPE)

typedef __attribute__((ext_vector_type(8))) short bfrag8;
typedef __attribute__((ext_vector_type(4))) float facc4;
typedef __attribute__((ext_vector_type(4))) float f4v;

static __device__ __forceinline__ unsigned short f2bf(float f) {
    unsigned int u = __float_as_uint(f);
    u += 0x7fffu + ((u >> 16) & 1u);   // RNE
    return (unsigned short)(u >> 16);
}
static __device__ __forceinline__ unsigned int pack2(float lo, float hi) {
    return (unsigned int)f2bf(lo) | ((unsigned int)f2bf(hi) << 16);
}
static __device__ __forceinline__ float bf2f(short u) {
    return __uint_as_float(((unsigned int)(unsigned short)u) << 16);
}
static __device__ __forceinline__ float dot4(f4v a, f4v b) {
    return a.x * b.x + a.y * b.y + a.z * b.z + a.w * b.w;
}
static __device__ __forceinline__ void gload16(const void* g, void* l) {
    __builtin_amdgcn_global_load_lds(
        (const __attribute__((address_space(1))) unsigned int*)g,
        (__attribute__((address_space(3))) unsigned int*)l, 16, 0, 0);
}

// ---- prep: z<3 transpose W_z -> bf16 (NxK); z==3 convert kn -> bf16 + zero ----
__global__ __launch_bounds__(256) void prep(
    const float* __restrict__ kn, const float* __restrict__ W0,
    const float* __restrict__ W1, const float* __restrict__ W2,
    unsigned short* __restrict__ knb, unsigned short* __restrict__ Wtall,
    int* __restrict__ zero_base)
{
    int z = blockIdx.z;
    int tx = threadIdx.x, ty = threadIdx.y;
    if (z == 3) {
        int b = blockIdx.y * 32 + blockIdx.x;
        int t = ty * 32 + tx;
        int gidx = b * 256 + t;
        if (gidx < ZERON) zero_base[gidx] = 0;        // fold counts+zdot zeroing here
        int idx = b * 1024 + t * 4;
        float4 a = *(const float4*)&kn[idx];
        uint2 o; o.x = pack2(a.x, a.y); o.y = pack2(a.z, a.w);
        *(uint2*)&knb[idx] = o;
        return;
    }
    const float* W = (z == 0) ? W0 : (z == 1) ? W1 : W2;
    unsigned short* Wt = Wtall + (size_t)z * KDIM * KDIM;
    __shared__ float tile[32][33];
    int nb = blockIdx.x * 32, kb = blockIdx.y * 32;
#pragma unroll
    for (int r0 = 0; r0 < 32; r0 += 8)
        tile[r0 + ty][tx] = W[(size_t)(kb + r0 + ty) * KDIM + nb + tx];
    __syncthreads();
#pragma unroll
    for (int r0 = 0; r0 < 32; r0 += 8)
        Wt[(size_t)(nb + r0 + ty) * KDIM + kb + tx] = f2bf(tile[tx][r0 + ty]);
}

// ---- scatter: direct fixed-capacity binning, src only (gemm-independent) ----
__global__ __launch_bounds__(256) void scatter_edges(
    const int* __restrict__ dir_src, const int* __restrict__ dir_dst,
    const int* __restrict__ und_src, const int* __restrict__ und_dst,
    const int* __restrict__ ek_src, const int* __restrict__ ek_dst,
    int* __restrict__ counts, int* __restrict__ edge_s)
{
    int i = blockIdx.x * 256 + threadIdx.x;
    int bin, s;
    if (i < E_DIRN) { bin = dir_dst[i]; s = dir_src[i]; }
    else if (i < E_DIRN + E_UNDN) {
        int loc = i - E_DIRN; bin = 1024 + und_dst[loc]; s = und_src[loc];
    } else if (i < TOT_E) {
        int loc = i - E_DIRN - E_UNDN; bin = 2048 + ek_dst[loc]; s = ek_src[loc] - E_N;
    } else return;
    int slot = atomicAdd(&counts[bin], 1);
    if (bin < 2048) {
        if (slot < CAPK) edge_s[(size_t)bin * CAPK + slot] = s;
    } else {
        if (slot < CAPE) edge_s[EKBASE + (size_t)(bin - 2048) * CAPE + slot] = s;
    }
}

// ---- MFMA GEMM, 64x64 tile, BK=64, 2-phase dbuf (unchanged) ----
__global__ __launch_bounds__(256) void gemm_mfma(
    const unsigned short* __restrict__ Ab,
    const unsigned short* __restrict__ Btall,
    const float* __restrict__ a_dir, const float* __restrict__ a_und,
    const float* __restrict__ a_ek,
    unsigned short* __restrict__ Zb, float* __restrict__ zdot)
{
    int z = blockIdx.z;
    const unsigned short* Bb = Btall + (size_t)z * KDIM * KDIM;
    unsigned short* C = Zb + (size_t)z * KDIM * KDIM;
    const float* avec = (z == 0) ? a_dir : (z == 1) ? a_und : a_ek;
    __shared__ alignas(16) unsigned short As[2][64 * 64];
    __shared__ alignas(16) unsigned short Bs[2][64 * 64];
    int tid = threadIdx.x;
    int lane = tid & 63, wv = tid >> 6;
    int wr = wv >> 1, wc = wv & 1;
    int tm = blockIdx.x * 64, tn = blockIdx.y * 64;
    int srow = lane >> 3, sch = lane & 7;
    facc4 acc[2][2] = {};

    auto stage = [&](int buf, int kk) {
#pragma unroll
        for (int t = 0; t < 2; ++t) {
            int r0 = wv * 16 + t * 8;
            int row = r0 + srow;
            gload16(&Ab[(size_t)(tm + row) * KDIM + kk + ((sch ^ (row & 7)) << 3)],
                    &As[buf][r0 * 64]);
        }
#pragma unroll
        for (int t = 0; t < 2; ++t) {
            int r0 = wv * 16 + t * 8;
            int row = r0 + srow;
            gload16(&Bb[(size_t)(tn + row) * KDIM + kk + ((sch ^ (row & 7)) << 3)],
                    &Bs[buf][r0 * 64]);
        }
    };
    auto compute = [&](int buf) {
#pragma unroll
        for (int ks = 0; ks < 2; ++ks) {
            bfrag8 af[2], bfr[2];
            int kch = ks * 4 + (lane >> 4);
#pragma unroll
            for (int f = 0; f < 2; ++f) {
                int ar = wr * 32 + f * 16 + (lane & 15);
                af[f] = *(const bfrag8*)&As[buf][ar * 64 + ((kch ^ (ar & 7)) << 3)];
                int bcol = wc * 32 + f * 16 + (lane & 15);
                bfr[f] = *(const bfrag8*)&Bs[buf][bcol * 64 + ((kch ^ (bcol & 7)) << 3)];
            }
#pragma unroll
            for (int i = 0; i < 2; ++i)
#pragma unroll
                for (int j = 0; j < 2; ++j)
                    acc[i][j] = __builtin_amdgcn_mfma_f32_16x16x32_bf16(af[i], bfr[j], acc[i][j], 0, 0, 0);
        }
    };

    stage(0, 0);
    __syncthreads();
    int cur = 0;
    for (int kk = 64; kk < KDIM; kk += 64) {
        stage(cur ^ 1, kk);
        compute(cur);
        __syncthreads();
        cur ^= 1;
    }
    compute(cur);

    int col0 = lane & 15, r0 = (lane >> 4) * 4;
    float av2[2];
#pragma unroll
    for (int j = 0; j < 2; ++j) av2[j] = avec[tn + wc * 32 + j * 16 + col0];
#pragma unroll
    for (int i = 0; i < 2; ++i)
#pragma unroll
        for (int j = 0; j < 2; ++j) {
            int row = tm + wr * 32 + i * 16 + r0;
            int col = tn + wc * 32 + j * 16 + col0;
#pragma unroll
            for (int r = 0; r < 4; ++r)
                C[(size_t)(row + r) * KDIM + col] = f2bf(acc[i][j][r]);
        }
#pragma unroll
    for (int i = 0; i < 2; ++i)
#pragma unroll
        for (int r = 0; r < 4; ++r) {
            float t = acc[i][0][r] * av2[0] + acc[i][1][r] * av2[1];
            t += __shfl_xor(t, 1); t += __shfl_xor(t, 2);
            t += __shfl_xor(t, 4); t += __shfl_xor(t, 8);
            if ((lane & 15) == 0)
                atomicAdd(&zdot[z * KDIM + tm + wr * 32 + i * 16 + r0 + r], t);
        }
}

// ---- merged gather: blocks [0,1024) = kn rows; rest = exer rows (wave-per-row) ----
// w = expf(zdot[...]) computed in-kernel from the 12KB hot table.
__global__ __launch_bounds__(256) void gather_all(
    const unsigned short* __restrict__ Zb, const int* __restrict__ edge_s,
    const int* __restrict__ counts, const float* __restrict__ zdot,
    const float* __restrict__ exer, const float* __restrict__ kn,
    const float* __restrict__ k_w1, const float* __restrict__ k_b1,
    const float* __restrict__ k_w2, const float* __restrict__ k_b2,
    const float* __restrict__ e_w1, const float* __restrict__ e_b1,
    float* __restrict__ out)
{
    __shared__ float bcs[2][KDIM];
    __shared__ float parts[4];
    int tid = threadIdx.x;
    if (blockIdx.x < KDIM) {
        // ---------------- kn path: one block per row, 4 waves ----------------
        int row = blockIdx.x;
        int wv = tid >> 6, lane = tid & 63;
        int g = wv >> 1, half = wv & 1;
        int bin = (g << 10) + row;
        int n = min(counts[bin], CAPK);
        size_t start = (size_t)bin * CAPK;
        const float* zd = zdot + g * KDIM;
        const bfrag8* Zp = (const bfrag8*)(Zb + (size_t)g * KDIM * KDIM) + half * 64 + lane;
        float b8[8] = {};
        float den = 0.f;
        for (int c0 = 0; c0 < n; c0 += 64) {
            int m = min(64, n - c0);
            int s = 0;
            if (lane < m) s = edge_s[start + c0 + lane];
            int j = 0;
            for (; j + 4 <= m; j += 4) {
                int   s0 = __shfl(s, j), s1 = __shfl(s, j+1), s2 = __shfl(s, j+2), s3 = __shfl(s, j+3);
                float w0 = __expf(zd[s0]), w1 = __expf(zd[s1]);
                float w2 = __expf(zd[s2]), w3 = __expf(zd[s3]);
                bfrag8 v0 = Zp[(size_t)s0 * 128], v1 = Zp[(size_t)s1 * 128];
                bfrag8 v2 = Zp[(size_t)s2 * 128], v3 = Zp[(size_t)s3 * 128];
#pragma unroll
                for (int k = 0; k < 8; ++k)
                    b8[k] += w0*bf2f(v0[k]) + w1*bf2f(v1[k]) + w2*bf2f(v2[k]) + w3*bf2f(v3[k]);
                den += w0 + w1 + w2 + w3;
            }
            for (; j + 2 <= m; j += 2) {
                int   s0 = __shfl(s, j), s1 = __shfl(s, j+1);
                float w0 = __expf(zd[s0]), w1 = __expf(zd[s1]);
                bfrag8 v0 = Zp[(size_t)s0 * 128], v1 = Zp[(size_t)s1 * 128];
#pragma unroll
                for (int k = 0; k < 8; ++k) b8[k] += w0*bf2f(v0[k]) + w1*bf2f(v1[k]);
                den += w0 + w1;
            }
            if (j < m) {
                int   s0 = __shfl(s, j);
                float w0 = __expf(zd[s0]);
                bfrag8 v0 = Zp[(size_t)s0 * 128];
#pragma unroll
                for (int k = 0; k < 8; ++k) b8[k] += w0*bf2f(v0[k]);
                den += w0;
            }
        }
        float inv = (n > 0) ? 1.f / den : 0.f;
#pragma unroll
        for (int k = 0; k < 8; ++k) b8[k] *= inv;
        const float* wvp = g ? k_w2 : k_w1;
        int cb = half * 512 + lane * 8;
        f4v A0 = *(const f4v*)&kn[(size_t)row * KDIM + cb];
        f4v A1 = *(const f4v*)&kn[(size_t)row * KDIM + cb + 4];
        f4v wa0 = *(const f4v*)&wvp[cb];
        f4v wa1 = *(const f4v*)&wvp[cb + 4];
        f4v wb0 = *(const f4v*)&wvp[KDIM + cb];
        f4v wb1 = *(const f4v*)&wvp[KDIM + cb + 4];
        f4v bb0 = {b8[0], b8[1], b8[2], b8[3]};
        f4v bb1 = {b8[4], b8[5], b8[6], b8[7]};
        float p = dot4(A0, wa0) + dot4(A1, wa1) + dot4(bb0, wb0) + dot4(bb1, wb1);
#pragma unroll
        for (int off = 32; off > 0; off >>= 1) p += __shfl_xor(p, off);
        if (lane == 0) parts[wv] = p;
        *(f4v*)&bcs[g][cb] = bb0;
        *(f4v*)&bcs[g][cb + 4] = bb1;
        __syncthreads();
        float s1 = parts[0] + parts[1] + k_b1[0];
        float s2 = parts[2] + parts[3] + k_b2[0];
        float mx = fmaxf(s1, s2);
        float e1 = expf(s1 - mx), e2 = expf(s2 - mx);
        float isum = 1.f / (e1 + e2);
        float sc0 = e1 * isum, sc1 = e2 * isum;
        int col = tid * 4;
        f4v A = *(const f4v*)&kn[(size_t)row * KDIM + col];
        f4v B = *(const f4v*)&bcs[0][col];
        f4v Cc = *(const f4v*)&bcs[1][col];
        *(f4v*)&out[(size_t)(E_N + row) * KDIM + col] = A + sc0 * B + sc1 * Cc;
        return;
    }
    // ---------------- exer path: one wave per row, nt streams ----------------
    int row = ((blockIdx.x - KDIM) * 256 + tid) >> 6;
    int lane = tid & 63;
    int n = min(counts[2048 + row], CAPE);
    size_t start = EKBASE + (size_t)row * CAPE;
    const float* zde = zdot + 2 * KDIM;
    const f4v* xr = (const f4v*)&exer[(size_t)row * KDIM];
    f4v x00 = __builtin_nontemporal_load(xr + 2 * lane);
    f4v x01 = __builtin_nontemporal_load(xr + 2 * lane + 1);
    f4v x10 = __builtin_nontemporal_load(xr + 2 * lane + 128);
    f4v x11 = __builtin_nontemporal_load(xr + 2 * lane + 129);
    const bfrag8* Zp = (const bfrag8*)(Zb + (size_t)2 * KDIM * KDIM);
    float b0[8] = {}, b1[8] = {};
    float den = 0.f;
    {
        int s = 0;
        if (lane < n) s = edge_s[start + lane];
        int j = 0;
        for (; j + 4 <= n; j += 4) {
            int   s0 = __shfl(s, j), s1 = __shfl(s, j+1), s2 = __shfl(s, j+2), s3 = __shfl(s, j+3);
            float w0 = __expf(zde[s0]), w1 = __expf(zde[s1]);
            float w2 = __expf(zde[s2]), w3 = __expf(zde[s3]);
            const bfrag8* z0 = Zp + (size_t)s0 * 128;
            const bfrag8* z1 = Zp + (size_t)s1 * 128;
            const bfrag8* z2 = Zp + (size_t)s2 * 128;
            const bfrag8* z3 = Zp + (size_t)s3 * 128;
            bfrag8 a0 = z0[lane], a1 = z0[lane + 64];
            bfrag8 c0v = z1[lane], c1 = z1[lane + 64];
            bfrag8 d0 = z2[lane], d1 = z2[lane + 64];
            bfrag8 e0 = z3[lane], e1 = z3[lane + 64];
#pragma unroll
            for (int k = 0; k < 8; ++k) {
                b0[k] += w0*bf2f(a0[k]) + w1*bf2f(c0v[k]) + w2*bf2f(d0[k]) + w3*bf2f(e0[k]);
                b1[k] += w0*bf2f(a1[k]) + w1*bf2f(c1[k]) + w2*bf2f(d1[k]) + w3*bf2f(e1[k]);
            }
            den += w0 + w1 + w2 + w3;
        }
        for (; j + 2 <= n; j += 2) {
            int   s0 = __shfl(s, j), s1 = __shfl(s, j+1);
            float w0 = __expf(zde[s0]), w1 = __expf(zde[s1]);
            const bfrag8* z0 = Zp + (size_t)s0 * 128;
            const bfrag8* z1 = Zp + (size_t)s1 * 128;
            bfrag8 a0 = z0[lane], a1 = z0[lane + 64];
            bfrag8 c0v = z1[lane], c1 = z1[lane + 64];
#pragma unroll
            for (int k = 0; k < 8; ++k) {
                b0[k] += w0*bf2f(a0[k]) + w1*bf2f(c0v[k]);
                b1[k] += w0*bf2f(a1[k]) + w1*bf2f(c1[k]);
            }
            den += w0 + w1;
        }
        if (j < n) {
            int   s0 = __shfl(s, j);
            float w0 = __expf(zde[s0]);
            const bfrag8* z0 = Zp + (size_t)s0 * 128;
            bfrag8 a0 = z0[lane], a1 = z0[lane + 64];
#pragma unroll
            for (int k = 0; k < 8; ++k) {
                b0[k] += w0*bf2f(a0[k]);
                b1[k] += w0*bf2f(a1[k]);
            }
            den += w0;
        }
    }
    float inv = (n > 0) ? 1.f / den : 0.f;
#pragma unroll
    for (int k = 0; k < 8; ++k) { b0[k] *= inv; b1[k] *= inv; }
    const f4v* wap = (const f4v*)e_w1;
    const f4v* wbp = (const f4v*)(e_w1 + KDIM);
    f4v wa0 = wap[2*lane], wa1 = wap[2*lane+1], wa2 = wap[2*lane+128], wa3 = wap[2*lane+129];
    f4v wb0 = wbp[2*lane], wb1 = wbp[2*lane+1], wb2 = wbp[2*lane+128], wb3 = wbp[2*lane+129];
    f4v bb0 = {b0[0], b0[1], b0[2], b0[3]};
    f4v bb1 = {b0[4], b0[5], b0[6], b0[7]};
    f4v bb2 = {b1[0], b1[1], b1[2], b1[3]};
    f4v bb3 = {b1[4], b1[5], b1[6], b1[7]};
    float p = dot4(x00, wa0) + dot4(x01, wa1) + dot4(x10, wa2) + dot4(x11, wa3)
            + dot4(bb0, wb0) + dot4(bb1, wb1) + dot4(bb2, wb2) + dot4(bb3, wb3);
#pragma unroll
    for (int off = 32; off > 0; off >>= 1) p += __shfl_xor(p, off);
    float se = p + e_b1[0];
    f4v* op = (f4v*)&out[(size_t)row * KDIM];
    __builtin_nontemporal_store(x00 + se * bb0, op + 2 * lane);
    __builtin_nontemporal_store(x01 + se * bb1, op + 2 * lane + 1);
    __builtin_nontemporal_store(x10 + se * bb2, op + 2 * lane + 128);
    __builtin_nontemporal_store(x11 + se * bb3, op + 2 * lane + 129);
}

extern "C" void kernel_launch(void* const* d_in, const int* in_sizes, int n_in,
                              void* d_out, int out_size, void* d_ws, size_t ws_size,
                              hipStream_t stream)
{
    (void)in_sizes; (void)n_in; (void)out_size; (void)ws_size;
    const float* exer  = (const float*)d_in[0];
    const float* kn    = (const float*)d_in[1];
    const int* dir_src = (const int*)d_in[2];
    const int* dir_dst = (const int*)d_in[3];
    const int* und_src = (const int*)d_in[4];
    const int* und_dst = (const int*)d_in[5];
    const int* ek_src  = (const int*)d_in[6];
    const int* ek_dst  = (const int*)d_in[7];
    const float* W_dir = (const float*)d_in[8];
    const float* a_dir = (const float*)d_in[9];
    const float* W_und = (const float*)d_in[10];
    const float* a_und = (const float*)d_in[11];
    const float* W_ek  = (const float*)d_in[12];
    const float* a_ek  = (const float*)d_in[13];
    const float* k_w1  = (const float*)d_in[14];
    const float* k_b1  = (const float*)d_in[15];
    const float* k_w2  = (const float*)d_in[16];
    const float* k_b2  = (const float*)d_in[17];
    const float* e_w1  = (const float*)d_in[18];
    const float* e_b1  = (const float*)d_in[19];

    char* ws = (char*)d_ws;
    unsigned short* Zb = (unsigned short*)ws; ws += (size_t)3 * KDIM * KDIM * 2;
    float* zdot    = (float*)ws; ws += 3 * KDIM * 4;          // contiguous with counts
    int* counts    = (int*)ws;   ws += NB * 4;
    int* edge_s    = (int*)ws;   ws += (size_t)NEDGE_SLOTS * 4;
    unsigned short* knb = (unsigned short*)ws; ws += (size_t)KDIM * KDIM * 2;
    unsigned short* Wtb = (unsigned short*)ws; ws += (size_t)3 * KDIM * KDIM * 2;

    prep<<<dim3(32, 32, 4), dim3(32, 8), 0, stream>>>(kn, W_dir, W_und, W_ek,
                                                      knb, Wtb, (int*)zdot);
    int eb = (TOT_E + 255) / 256;
    scatter_edges<<<eb, 256, 0, stream>>>(dir_src, dir_dst, und_src, und_dst,
                                          ek_src, ek_dst, counts, edge_s);
    gemm_mfma<<<dim3(16, 16, 3), 256, 0, stream>>>(knb, Wtb, a_dir, a_und, a_ek,
                                                   Zb, zdot);
    float* out = (float*)d_out;
    gather_all<<<KDIM + 7500, 256, 0, stream>>>(Zb, edge_s, counts, zdot,
                                                exer, kn, k_w1, k_b1, k_w2, k_b2,
                                                e_w1, e_b1, out);
}

// Round 14
// 129.914 us; speedup vs baseline: 1.0332x; 1.0332x over previous
//
#include <hip/hip_runtime.h>

#define E_N 30000
#define KDIM 1024
#define E_DIRN 65536
#define E_UNDN 65536
#define E_EKN 120000
#define NB (1024 + 1024 + E_N)            // 32048 bins
#define TOT_E (E_DIRN + E_UNDN + E_EKN)   // 251072
#define ZERON (3 * KDIM + NB)             // zdot + counts words to zero
#define CAPK 192                          // per-bin capacity, dir/und (mean 64, max~104)
#define CAPE 32                           // per-bin capacity, ek (mean 4, P(>=32)~1e-18)
#define EKBASE (2048 * CAPK)              // 393216
#define NEDGE_SLOTS (EKBASE + E_N * CAPE)

typedef __attribute__((ext_vector_type(8))) short bfrag8;
typedef __attribute__((ext_vector_type(4))) float facc4;
typedef __attribute__((ext_vector_type(4))) float f4v;

static __device__ __forceinline__ unsigned short f2bf(float f) {
    unsigned int u = __float_as_uint(f);
    u += 0x7fffu + ((u >> 16) & 1u);   // RNE
    return (unsigned short)(u >> 16);
}
static __device__ __forceinline__ unsigned int pack2(float lo, float hi) {
    return (unsigned int)f2bf(lo) | ((unsigned int)f2bf(hi) << 16);
}
static __device__ __forceinline__ float bf2f(short u) {
    return __uint_as_float(((unsigned int)(unsigned short)u) << 16);
}
static __device__ __forceinline__ float dot4(f4v a, f4v b) {
    return a.x * b.x + a.y * b.y + a.z * b.z + a.w * b.w;
}
static __device__ __forceinline__ void gload16(const void* g, void* l) {
    __builtin_amdgcn_global_load_lds(
        (const __attribute__((address_space(1))) unsigned int*)g,
        (__attribute__((address_space(3))) unsigned int*)l, 16, 0, 0);
}

// ---- prep: z<3 transpose W_z -> bf16 (NxK); z==3 convert kn -> bf16; z==4 zero ----
__global__ __launch_bounds__(256) void prep(
    const float* __restrict__ kn, const float* __restrict__ W0,
    const float* __restrict__ W1, const float* __restrict__ W2,
    unsigned short* __restrict__ knb, unsigned short* __restrict__ Wtall,
    int* __restrict__ zero_base)
{
    int z = blockIdx.z;
    int tx = threadIdx.x, ty = threadIdx.y;
    if (z == 4) {
        int idx = (blockIdx.y * 32 + blockIdx.x) * 256 + ty * 32 + tx;
        if (idx < ZERON) zero_base[idx] = 0;
        return;
    }
    if (z == 3) {
        int b = blockIdx.y * 32 + blockIdx.x;
        int t = ty * 32 + tx;
        int idx = b * 1024 + t * 4;
        float4 a = *(const float4*)&kn[idx];
        uint2 o; o.x = pack2(a.x, a.y); o.y = pack2(a.z, a.w);
        *(uint2*)&knb[idx] = o;
        return;
    }
    const float* W = (z == 0) ? W0 : (z == 1) ? W1 : W2;
    unsigned short* Wt = Wtall + (size_t)z * KDIM * KDIM;
    __shared__ float tile[32][33];
    int nb = blockIdx.x * 32, kb = blockIdx.y * 32;
#pragma unroll
    for (int r0 = 0; r0 < 32; r0 += 8)
        tile[r0 + ty][tx] = W[(size_t)(kb + r0 + ty) * KDIM + nb + tx];
    __syncthreads();
#pragma unroll
    for (int r0 = 0; r0 < 32; r0 += 8)
        Wt[(size_t)(nb + r0 + ty) * KDIM + kb + tx] = f2bf(tile[tx][r0 + ty]);
}

// ---- MFMA GEMM, 64x64 tile, BK=64, 2-phase dbuf ----
__global__ __launch_bounds__(256) void gemm_mfma(
    const unsigned short* __restrict__ Ab,
    const unsigned short* __restrict__ Btall,
    const float* __restrict__ a_dir, const float* __restrict__ a_und,
    const float* __restrict__ a_ek,
    unsigned short* __restrict__ Zb, float* __restrict__ zdot)
{
    int z = blockIdx.z;
    const unsigned short* Bb = Btall + (size_t)z * KDIM * KDIM;
    unsigned short* C = Zb + (size_t)z * KDIM * KDIM;
    const float* avec = (z == 0) ? a_dir : (z == 1) ? a_und : a_ek;
    __shared__ alignas(16) unsigned short As[2][64 * 64];
    __shared__ alignas(16) unsigned short Bs[2][64 * 64];
    int tid = threadIdx.x;
    int lane = tid & 63, wv = tid >> 6;
    int wr = wv >> 1, wc = wv & 1;
    int tm = blockIdx.x * 64, tn = blockIdx.y * 64;
    int srow = lane >> 3, sch = lane & 7;
    facc4 acc[2][2] = {};

    auto stage = [&](int buf, int kk) {
#pragma unroll
        for (int t = 0; t < 2; ++t) {
            int r0 = wv * 16 + t * 8;
            int row = r0 + srow;
            gload16(&Ab[(size_t)(tm + row) * KDIM + kk + ((sch ^ (row & 7)) << 3)],
                    &As[buf][r0 * 64]);
        }
#pragma unroll
        for (int t = 0; t < 2; ++t) {
            int r0 = wv * 16 + t * 8;
            int row = r0 + srow;
            gload16(&Bb[(size_t)(tn + row) * KDIM + kk + ((sch ^ (row & 7)) << 3)],
                    &Bs[buf][r0 * 64]);
        }
    };
    auto compute = [&](int buf) {
#pragma unroll
        for (int ks = 0; ks < 2; ++ks) {
            bfrag8 af[2], bfr[2];
            int kch = ks * 4 + (lane >> 4);
#pragma unroll
            for (int f = 0; f < 2; ++f) {
                int ar = wr * 32 + f * 16 + (lane & 15);
                af[f] = *(const bfrag8*)&As[buf][ar * 64 + ((kch ^ (ar & 7)) << 3)];
                int bcol = wc * 32 + f * 16 + (lane & 15);
                bfr[f] = *(const bfrag8*)&Bs[buf][bcol * 64 + ((kch ^ (bcol & 7)) << 3)];
            }
#pragma unroll
            for (int i = 0; i < 2; ++i)
#pragma unroll
                for (int j = 0; j < 2; ++j)
                    acc[i][j] = __builtin_amdgcn_mfma_f32_16x16x32_bf16(af[i], bfr[j], acc[i][j], 0, 0, 0);
        }
    };

    stage(0, 0);
    __syncthreads();
    int cur = 0;
    for (int kk = 64; kk < KDIM; kk += 64) {
        stage(cur ^ 1, kk);          // next tile in flight during MFMA
        compute(cur);
        __syncthreads();
        cur ^= 1;
    }
    compute(cur);

    int col0 = lane & 15, r0 = (lane >> 4) * 4;
    float av2[2];
#pragma unroll
    for (int j = 0; j < 2; ++j) av2[j] = avec[tn + wc * 32 + j * 16 + col0];
#pragma unroll
    for (int i = 0; i < 2; ++i)
#pragma unroll
        for (int j = 0; j < 2; ++j) {
            int row = tm + wr * 32 + i * 16 + r0;
            int col = tn + wc * 32 + j * 16 + col0;
#pragma unroll
            for (int r = 0; r < 4; ++r)
                C[(size_t)(row + r) * KDIM + col] = f2bf(acc[i][j][r]);
        }
#pragma unroll
    for (int i = 0; i < 2; ++i)
#pragma unroll
        for (int r = 0; r < 4; ++r) {
            float t = acc[i][0][r] * av2[0] + acc[i][1][r] * av2[1];
            t += __shfl_xor(t, 1); t += __shfl_xor(t, 2);
            t += __shfl_xor(t, 4); t += __shfl_xor(t, 8);
            if ((lane & 15) == 0)
                atomicAdd(&zdot[z * KDIM + tm + wr * 32 + i * 16 + r0 + r], t);
        }
}

// ---- scatter: direct fixed-capacity binning ----
__global__ __launch_bounds__(256) void scatter_edges(
    const int* __restrict__ dir_src, const int* __restrict__ dir_dst,
    const int* __restrict__ und_src, const int* __restrict__ und_dst,
    const int* __restrict__ ek_src, const int* __restrict__ ek_dst,
    const float* __restrict__ zdot, int* __restrict__ counts,
    int2* __restrict__ edge_sw)
{
    int i = blockIdx.x * 256 + threadIdx.x;
    int bin, s; float w;
    if (i < E_DIRN) { bin = dir_dst[i]; s = dir_src[i]; w = expf(zdot[s]); }
    else if (i < E_DIRN + E_UNDN) {
        int loc = i - E_DIRN; bin = 1024 + und_dst[loc]; s = und_src[loc]; w = expf(zdot[1024 + s]);
    } else if (i < TOT_E) {
        int loc = i - E_DIRN - E_UNDN; bin = 2048 + ek_dst[loc]; s = ek_src[loc] - E_N; w = expf(zdot[2048 + s]);
    } else return;
    int slot = atomicAdd(&counts[bin], 1);
    if (bin < 2048) {
        if (slot < CAPK) edge_sw[(size_t)bin * CAPK + slot] = make_int2(s, __float_as_int(w));
    } else {
        if (slot < CAPE) edge_sw[EKBASE + (size_t)(bin - 2048) * CAPE + slot] = make_int2(s, __float_as_int(w));
    }
}

// ---- merged gather: blocks [0,1024) = kn rows; rest = exer rows (wave-per-row) ----
__global__ __launch_bounds__(256) void gather_all(
    const unsigned short* __restrict__ Zb, const int2* __restrict__ edge_sw,
    const int* __restrict__ counts,
    const float* __restrict__ exer, const float* __restrict__ kn,
    const float* __restrict__ k_w1, const float* __restrict__ k_b1,
    const float* __restrict__ k_w2, const float* __restrict__ k_b2,
    const float* __restrict__ e_w1, const float* __restrict__ e_b1,
    float* __restrict__ out)
{
    __shared__ float bcs[2][KDIM];
    __shared__ float parts[4];
    int tid = threadIdx.x;
    if (blockIdx.x < KDIM) {
        // ---------------- kn path: one block per row, 4 waves ----------------
        int row = blockIdx.x;
        int wv = tid >> 6, lane = tid & 63;
        int g = wv >> 1, half = wv & 1;
        int bin = (g << 10) + row;
        int n = min(counts[bin], CAPK);
        size_t start = (size_t)bin * CAPK;
        const bfrag8* Zp = (const bfrag8*)(Zb + (size_t)g * KDIM * KDIM) + half * 64 + lane;
        float b8[8] = {};
        float den = 0.f;
        for (int c0 = 0; c0 < n; c0 += 64) {
            int m = min(64, n - c0);
            int s = 0; float w = 0.f;
            if (lane < m) {
                int2 ew = edge_sw[start + c0 + lane];
                s = ew.x; w = __int_as_float(ew.y);
            }
            int j = 0;
            for (; j + 4 <= m; j += 4) {
                int   s0 = __shfl(s, j), s1 = __shfl(s, j+1), s2 = __shfl(s, j+2), s3 = __shfl(s, j+3);
                float w0 = __shfl(w, j), w1 = __shfl(w, j+1), w2 = __shfl(w, j+2), w3 = __shfl(w, j+3);
                bfrag8 v0 = Zp[(size_t)s0 * 128], v1 = Zp[(size_t)s1 * 128];
                bfrag8 v2 = Zp[(size_t)s2 * 128], v3 = Zp[(size_t)s3 * 128];
#pragma unroll
                for (int k = 0; k < 8; ++k)
                    b8[k] += w0*bf2f(v0[k]) + w1*bf2f(v1[k]) + w2*bf2f(v2[k]) + w3*bf2f(v3[k]);
                den += w0 + w1 + w2 + w3;
            }
            for (; j + 2 <= m; j += 2) {
                int   s0 = __shfl(s, j), s1 = __shfl(s, j+1);
                float w0 = __shfl(w, j), w1 = __shfl(w, j+1);
                bfrag8 v0 = Zp[(size_t)s0 * 128], v1 = Zp[(size_t)s1 * 128];
#pragma unroll
                for (int k = 0; k < 8; ++k) b8[k] += w0*bf2f(v0[k]) + w1*bf2f(v1[k]);
                den += w0 + w1;
            }
            if (j < m) {
                int   s0 = __shfl(s, j);
                float w0 = __shfl(w, j);
                bfrag8 v0 = Zp[(size_t)s0 * 128];
#pragma unroll
                for (int k = 0; k < 8; ++k) b8[k] += w0*bf2f(v0[k]);
                den += w0;
            }
        }
        float inv = (n > 0) ? 1.f / den : 0.f;
#pragma unroll
        for (int k = 0; k < 8; ++k) b8[k] *= inv;
        const float* wvp = g ? k_w2 : k_w1;
        int cb = half * 512 + lane * 8;
        f4v A0 = *(const f4v*)&kn[(size_t)row * KDIM + cb];
        f4v A1 = *(const f4v*)&kn[(size_t)row * KDIM + cb + 4];
        f4v wa0 = *(const f4v*)&wvp[cb];
        f4v wa1 = *(const f4v*)&wvp[cb + 4];
        f4v wb0 = *(const f4v*)&wvp[KDIM + cb];
        f4v wb1 = *(const f4v*)&wvp[KDIM + cb + 4];
        f4v bb0 = {b8[0], b8[1], b8[2], b8[3]};
        f4v bb1 = {b8[4], b8[5], b8[6], b8[7]};
        float p = dot4(A0, wa0) + dot4(A1, wa1) + dot4(bb0, wb0) + dot4(bb1, wb1);
#pragma unroll
        for (int off = 32; off > 0; off >>= 1) p += __shfl_xor(p, off);
        if (lane == 0) parts[wv] = p;
        *(f4v*)&bcs[g][cb] = bb0;
        *(f4v*)&bcs[g][cb + 4] = bb1;
        __syncthreads();
        float s1 = parts[0] + parts[1] + k_b1[0];
        float s2 = parts[2] + parts[3] + k_b2[0];
        float mx = fmaxf(s1, s2);
        float e1 = expf(s1 - mx), e2 = expf(s2 - mx);
        float isum = 1.f / (e1 + e2);
        float sc0 = e1 * isum, sc1 = e2 * isum;
        int col = tid * 4;
        f4v A = *(const f4v*)&kn[(size_t)row * KDIM + col];
        f4v B = *(const f4v*)&bcs[0][col];
        f4v Cc = *(const f4v*)&bcs[1][col];
        *(f4v*)&out[(size_t)(E_N + row) * KDIM + col] = A + sc0 * B + sc1 * Cc;
        return;
    }
    // ---------------- exer path: one wave per row, n <= CAPE (single chunk) ----------
    int row = ((blockIdx.x - KDIM) * 256 + tid) >> 6;
    int lane = tid & 63;
    int n = min(counts[2048 + row], CAPE);
    size_t start = EKBASE + (size_t)row * CAPE;
    const f4v* xr = (const f4v*)&exer[(size_t)row * KDIM];
    f4v x00 = xr[2 * lane];
    f4v x01 = xr[2 * lane + 1];
    f4v x10 = xr[2 * lane + 128];
    f4v x11 = xr[2 * lane + 129];
    const bfrag8* Zp = (const bfrag8*)(Zb + (size_t)2 * KDIM * KDIM);
    float b0[8] = {}, b1[8] = {};
    float den = 0.f;
    {
        int s = 0; float w = 0.f;
        if (lane < n) {
            int2 ew = edge_sw[start + lane];
            s = ew.x; w = __int_as_float(ew.y);
        }
        int j = 0;
        for (; j + 4 <= n; j += 4) {
            int   s0 = __shfl(s, j), s1 = __shfl(s, j+1), s2 = __shfl(s, j+2), s3 = __shfl(s, j+3);
            float w0 = __shfl(w, j), w1 = __shfl(w, j+1), w2 = __shfl(w, j+2), w3 = __shfl(w, j+3);
            const bfrag8* z0 = Zp + (size_t)s0 * 128;
            const bfrag8* z1 = Zp + (size_t)s1 * 128;
            const bfrag8* z2 = Zp + (size_t)s2 * 128;
            const bfrag8* z3 = Zp + (size_t)s3 * 128;
            bfrag8 a0 = z0[lane], a1 = z0[lane + 64];
            bfrag8 c0v = z1[lane], c1 = z1[lane + 64];
            bfrag8 d0 = z2[lane], d1 = z2[lane + 64];
            bfrag8 e0 = z3[lane], e1 = z3[lane + 64];
#pragma unroll
            for (int k = 0; k < 8; ++k) {
                b0[k] += w0*bf2f(a0[k]) + w1*bf2f(c0v[k]) + w2*bf2f(d0[k]) + w3*bf2f(e0[k]);
                b1[k] += w0*bf2f(a1[k]) + w1*bf2f(c1[k]) + w2*bf2f(d1[k]) + w3*bf2f(e1[k]);
            }
            den += w0 + w1 + w2 + w3;
        }
        for (; j + 2 <= n; j += 2) {
            int   s0 = __shfl(s, j), s1 = __shfl(s, j+1);
            float w0 = __shfl(w, j), w1 = __shfl(w, j+1);
            const bfrag8* z0 = Zp + (size_t)s0 * 128;
            const bfrag8* z1 = Zp + (size_t)s1 * 128;
            bfrag8 a0 = z0[lane], a1 = z0[lane + 64];
            bfrag8 c0v = z1[lane], c1 = z1[lane + 64];
#pragma unroll
            for (int k = 0; k < 8; ++k) {
                b0[k] += w0*bf2f(a0[k]) + w1*bf2f(c0v[k]);
                b1[k] += w0*bf2f(a1[k]) + w1*bf2f(c1[k]);
            }
            den += w0 + w1;
        }
        if (j < n) {
            int   s0 = __shfl(s, j);
            float w0 = __shfl(w, j);
            const bfrag8* z0 = Zp + (size_t)s0 * 128;
            bfrag8 a0 = z0[lane], a1 = z0[lane + 64];
#pragma unroll
            for (int k = 0; k < 8; ++k) {
                b0[k] += w0*bf2f(a0[k]);
                b1[k] += w0*bf2f(a1[k]);
            }
            den += w0;
        }
    }
    float inv = (n > 0) ? 1.f / den : 0.f;
#pragma unroll
    for (int k = 0; k < 8; ++k) { b0[k] *= inv; b1[k] *= inv; }
    const f4v* wap = (const f4v*)e_w1;
    const f4v* wbp = (const f4v*)(e_w1 + KDIM);
    f4v wa0 = wap[2*lane], wa1 = wap[2*lane+1], wa2 = wap[2*lane+128], wa3 = wap[2*lane+129];
    f4v wb0 = wbp[2*lane], wb1 = wbp[2*lane+1], wb2 = wbp[2*lane+128], wb3 = wbp[2*lane+129];
    f4v bb0 = {b0[0], b0[1], b0[2], b0[3]};
    f4v bb1 = {b0[4], b0[5], b0[6], b0[7]};
    f4v bb2 = {b1[0], b1[1], b1[2], b1[3]};
    f4v bb3 = {b1[4], b1[5], b1[6], b1[7]};
    float p = dot4(x00, wa0) + dot4(x01, wa1) + dot4(x10, wa2) + dot4(x11, wa3)
            + dot4(bb0, wb0) + dot4(bb1, wb1) + dot4(bb2, wb2) + dot4(bb3, wb3);
#pragma unroll
    for (int off = 32; off > 0; off >>= 1) p += __shfl_xor(p, off);
    float se = p + e_b1[0];
    f4v* op = (f4v*)&out[(size_t)row * KDIM];
    op[2 * lane]       = x00 + se * bb0;
    op[2 * lane + 1]   = x01 + se * bb1;
    op[2 * lane + 128] = x10 + se * bb2;
    op[2 * lane + 129] = x11 + se * bb3;
}

extern "C" void kernel_launch(void* const* d_in, const int* in_sizes, int n_in,
                              void* d_out, int out_size, void* d_ws, size_t ws_size,
                              hipStream_t stream)
{
    (void)in_sizes; (void)n_in; (void)out_size; (void)ws_size;
    const float* exer  = (const float*)d_in[0];
    const float* kn    = (const float*)d_in[1];
    const int* dir_src = (const int*)d_in[2];
    const int* dir_dst = (const int*)d_in[3];
    const int* und_src = (const int*)d_in[4];
    const int* und_dst = (const int*)d_in[5];
    const int* ek_src  = (const int*)d_in[6];
    const int* ek_dst  = (const int*)d_in[7];
    const float* W_dir = (const float*)d_in[8];
    const float* a_dir = (const float*)d_in[9];
    const float* W_und = (const float*)d_in[10];
    const float* a_und = (const float*)d_in[11];
    const float* W_ek  = (const float*)d_in[12];
    const float* a_ek  = (const float*)d_in[13];
    const float* k_w1  = (const float*)d_in[14];
    const float* k_b1  = (const float*)d_in[15];
    const float* k_w2  = (const float*)d_in[16];
    const float* k_b2  = (const float*)d_in[17];
    const float* e_w1  = (const float*)d_in[18];
    const float* e_b1  = (const float*)d_in[19];

    char* ws = (char*)d_ws;
    unsigned short* Zb = (unsigned short*)ws; ws += (size_t)3 * KDIM * KDIM * 2;
    float* zdot    = (float*)ws; ws += 3 * KDIM * 4;          // contiguous with counts
    int* counts    = (int*)ws;   ws += NB * 4;
    int2* edge_sw  = (int2*)ws;  ws += (size_t)NEDGE_SLOTS * 8;
    unsigned short* knb = (unsigned short*)ws; ws += (size_t)KDIM * KDIM * 2;
    unsigned short* Wtb = (unsigned short*)ws; ws += (size_t)3 * KDIM * KDIM * 2;

    prep<<<dim3(32, 32, 5), dim3(32, 8), 0, stream>>>(kn, W_dir, W_und, W_ek,
                                                      knb, Wtb, (int*)zdot);
    gemm_mfma<<<dim3(16, 16, 3), 256, 0, stream>>>(knb, Wtb, a_dir, a_und, a_ek,
                                                   Zb, zdot);
    int eb = (TOT_E + 255) / 256;
    scatter_edges<<<eb, 256, 0, stream>>>(dir_src, dir_dst, und_src, und_dst,
                                          ek_src, ek_dst, zdot, counts, edge_sw);

    float* out = (float*)d_out;
    gather_all<<<KDIM + 7500, 256, 0, stream>>>(Zb, edge_sw, counts,
                                                exer, kn, k_w1, k_b1, k_w2, k_b2,
                                                e_w1, e_b1, out);
}